// Round 19
// baseline (17.063 us; speedup 1.0000x reference)
//
#include <hip/hip_runtime.h>

#define SN 128
#define SPK 512

constexpr float GMIN  = 0.1f;
constexpr float PFRAC = 0.3f;
constexpr float GMAX  = 1.0f;

// LDS-composed tiles, 4 slots per block, prep amortized.
// Lazy decay: v(n) = C(n)*a + GMIN, C(n) = exp((ts0-ts[n])/TAU) <= 1.
// Untouched cell at snapshot r: u_r = GMIN*(1-C_r) (identical everywhere).
// Touch at n: a' = (1-PFRAC)*a + PFRAC*(GMAX-GMIN)/C(n); amplitude is
// non-decreasing over the touch prefix -> per-touch own-prefix candidates +
// max reproduce the exact final value (verified absmax 0.0, R11/R17/R18).
// Same-cell predecessors: hash-count buckets; only events in buckets with
// count>=2 are compacted (time order) and scanned (no false negatives).
//
// Block = (s, slot-quad): prep ONCE (loads/hash/snlast/compact/amplitudes),
// then 4x {memset 32KB tile to u_r -> LDS atomicMax scatter -> coalesced
// writeout overlapped with next memset} on double-buffered tiles.
// 256 blocks x 1024 threads; LDS ~70 KB; hash aliases tileA (dead after P2).

__global__ __launch_bounds__(1024, 4) void fuse_kernel(
    const int*   __restrict__ event,   // (SN, SPK, 3) int32: x, y, pol
    const float* __restrict__ ts,      // (SN, SPK) f32, ascending
    const int*   __restrict__ tt,      // (SN, SPK) int32 in [0,8)
    const int*   __restrict__ length,  // (SN,) int32
    float*       __restrict__ out)     // (SN, 8, 2, 64, 64) f32
{
    __shared__ int      tileA[8192];   // 32 KB
    __shared__ int      tileB[8192];   // 32 KB
    __shared__ float    stsn[SPK];
    __shared__ unsigned lpk [SPK];     // ambiguous list: (t<<16)|key, time order
    __shared__ float    lCr [SPK];
    __shared__ int      snl [8];
    __shared__ int      wcnt[16];
    __shared__ float    sC  [8];
    __shared__ int      sNr [8];
    __shared__ int      sUb [8];

    unsigned* hcnt = (unsigned*)tileA; // 4096 buckets = 16 KB (dead after P2)

    const int blk  = blockIdx.x;
    const int s    = blk >> 1;
    const int g0   = (blk & 1) * 4;    // slots g0..g0+3
    const int t    = threadIdx.x;      // 0..1023
    const int lane = t & 63;
    const int wid  = t >> 6;

    const int   len = length[s];
    const float ts0 = ts[s * SPK];

    // ---- P0: init hash + snl; issue event loads (threads 0..511) ----
#pragma unroll
    for (int k = 0; k < 4; ++k) hcnt[t + k * 1024] = 0u;
    if (t < 8) snl[t] = -1;

    int ex = 0, ey = 0, ep = 0; float tsn = 0.0f;
    bool gate = false; unsigned key = 0u, h = 0u; float myCr = 0.0f;
    int tv = 0;
    if (t < SPK) {
        const int* ev = event + (size_t)(s * SPK + t) * 3;
        ex = ev[0]; ey = ev[1]; ep = ev[2];
        tsn  = ts[s * SPK + t];
        tv   = tt[s * SPK + t];
        gate = (t < len);                               // t==0 always (len>=1)
        key  = (unsigned)((ep << 14) | (ex << 7) | ey);
        h    = (key * 2654435761u) >> 20;               // 12-bit bucket
        myCr = (PFRAC * (GMAX - GMIN)) * __expf(-(ts0 - tsn) * 0.01f); // 0.27/C
    }
    __syncthreads();

    // ---- P1: stage (LDS atomics) ----
    if (t < SPK) {
        stsn[t] = tsn;
        if (t >= 1) atomicMax(&snl[tv], t);
        if (gate)   atomicAdd(&hcnt[h], 1u);
    }
    __syncthreads();

    // ---- P2: ambiguity flags + per-slot tables ----
    const bool amb = (t < SPK) && gate && (hcnt[h] > 1u);
    const unsigned long long bm = __ballot(amb);
    if (lane == 0) wcnt[wid] = (int)__popcll(bm);
    if (t < 8) {
        int nr = snl[t];
        if (t == 0 && nr < 0) nr = 0;                   // slot0 -> init state
        float C = 0.0f, u = 0.0f;
        if (nr >= 0) {
            C = __expf((ts0 - stsn[nr]) * 0.01f);       // C_r <= 1
            u = GMIN - C * GMIN;                        // untouched value
        }
        sNr[t] = nr; sC[t] = C; sUb[t] = __float_as_int(u);
    }
    __syncthreads();                                    // hcnt dead from here

    // ---- P3: compact ambiguous events (time order) ----
    int base = 0, nA = 0;
#pragma unroll
    for (int w = 0; w < 16; ++w) {
        int c = wcnt[w];
        if (w < wid) base += c;
        nA += c;
    }
    if (amb) {
        int pos = base + (int)__popcll(bm & ((1ull << lane) - 1ull));
        lpk[pos] = ((unsigned)t << 16) | key;
        lCr[pos] = myCr;
    }
    __syncthreads();

    // ---- P4: per-event amplitude (register) + first memset ----
    float a = -GMIN;
    if (t < SPK && gate) {
        if (amb) {
            for (int i = 0; i < nA; ++i) {
                unsigned e = lpk[i];
                if ((e & 0xFFFFu) == key && (e >> 16) < (unsigned)t)
                    a = ((e >> 16) == 0u)
                            ? (PFRAC * (GMAX - GMIN) - GMIN)   // init SETs 0.27
                            : fmaf(1.0f - PFRAC, a, lCr[i]);
            }
        }
        a = (t == 0) ? (PFRAC * (GMAX - GMIN) - GMIN)
                     : fmaf(1.0f - PFRAC, a, myCr);
    }
    const int cell = (t < SPK) ? ((ep * 64 + (ex >> 1)) * 64 + (ey >> 1)) : 0;

    {   // memset slot g0 into tileA (vectorized)
        int4 u4; u4.x = u4.y = u4.z = u4.w = sUb[g0];
        int4* T = (int4*)tileA;
#pragma unroll
        for (int k = 0; k < 2; ++k) T[t + k * 1024] = u4;
    }
    __syncthreads();

    // ---- slot pipeline: scatter -> writeout || memset-next ----
#pragma unroll
    for (int i = 0; i < 4; ++i) {
        int*      cur = (i & 1) ? tileB : tileA;
        const int r   = g0 + i;

        if (t < SPK && gate && t <= sNr[r]) {
            float val = fmaf(sC[r], a, GMIN);           // >= u_r >= 0
            atomicMax(&cur[cell], __float_as_int(val));
        }
        __syncthreads();

        {   // writeout slot r (2048 float4)
            float4*       o4 = (float4*)(out + (size_t)(s * 8 + r) * 8192);
            const float4* t4 = (const float4*)cur;
#pragma unroll
            for (int k = 0; k < 2; ++k) o4[t + k * 1024] = t4[t + k * 1024];
        }
        if (i < 3) {                                    // memset next buffer
            int* nxt = (i & 1) ? tileA : tileB;
            int4 u4; u4.x = u4.y = u4.z = u4.w = sUb[r + 1];
            int4* T = (int4*)nxt;
#pragma unroll
            for (int k = 0; k < 2; ++k) T[t + k * 1024] = u4;
            __syncthreads();
        }
    }
}

extern "C" void kernel_launch(void* const* d_in, const int* in_sizes, int n_in,
                              void* d_out, int out_size, void* d_ws, size_t ws_size,
                              hipStream_t stream) {
    const int*   event  = (const int*)  d_in[0];
    const float* ts     = (const float*)d_in[1];
    const int*   tt     = (const int*)  d_in[2];
    const int*   length = (const int*)  d_in[3];
    float*       out    = (float*)d_out;

    // 128 samples x 2 slot-quads = 256 blocks x 1024 threads
    fuse_kernel<<<dim3(SN * 2), dim3(1024), 0, stream>>>(event, ts, tt, length, out);
}